// Round 10
// baseline (182.761 us; speedup 1.0000x reference)
//
#include <hip/hip_runtime.h>

// WalletGNN: 2-layer GCN, N=100000, E=800000, 128 -> 128 -> 64, fp32 in/out.
// R10: (1) nontemporal hints on stream-once data (col/dst/src/eb loads;
//      act/out/eb/col stores) to reserve per-XCD L2 for the H row table;
//      (2) scan chain 3 kernels -> 2 (per-bucket row scan + base scan),
//      bucket_csr reads bucket bounds from base[].

typedef __attribute__((ext_vector_type(8))) short bf16x8;
typedef __attribute__((ext_vector_type(4))) float f32x4;
typedef __attribute__((ext_vector_type(2))) unsigned u32x2;

static __device__ __forceinline__ unsigned short f2bf(float f) {
    unsigned u = __builtin_bit_cast(unsigned, f);
    u += 0x7fffu + ((u >> 16) & 1u);
    return (unsigned short)(u >> 16);
}
static __device__ __forceinline__ float bflo(unsigned u) {
    return __builtin_bit_cast(float, u << 16);
}
// {lo(x), hi(x)+junk, lo(y), hi(y)+junk} — junk mantissa < 2^-8 relative.
static __device__ __forceinline__ f32x4 bfquad(uint2 v) {
    f32x4 r;
    r[0] = bflo(v.x); r[1] = __builtin_bit_cast(float, v.x);
    r[2] = bflo(v.y); r[3] = __builtin_bit_cast(float, v.y);
    return r;
}

#define CHUNK 4096              // edges per partition block
#define NBUCKP 512              // padded bucket count (dst>>8 < 391)

// ---------- A1: per-block bucket histogram (+fused W^T bf16 prep) ----------
__global__ __launch_bounds__(256) void k_hist(const int* __restrict__ dst,
        int* __restrict__ ghist, int E, int nblk,
        const float* __restrict__ W1, const float* __restrict__ W2,
        unsigned short* __restrict__ W1t, unsigned short* __restrict__ W2t) {
    __shared__ int h[NBUCKP];
    const int tid = threadIdx.x, b = blockIdx.x;
    if (b >= nblk) {            // prep_w blocks
        int i = (b - nblk) * 256 + tid;
        if (i < 128 * 128) {
            int n = i >> 7, k = i & 127;
            W1t[i] = f2bf(W1[k * 128 + n]);
        }
        int j = i - 128 * 128;
        if (j >= 0 && j < 64 * 128) {
            int n = j >> 7, k = j & 127;
            W2t[j] = f2bf(W2[k * 64 + n]);
        }
        return;
    }
    h[tid] = 0; h[tid + 256] = 0;
    __syncthreads();
    const int base = b * CHUNK;
#pragma unroll
    for (int i = 0; i < CHUNK / 256; ++i) {
        int e = base + i * 256 + tid;
        if (e < E) atomicAdd(&h[__builtin_nontemporal_load(&dst[e]) >> 8], 1);
    }
    __syncthreads();
    ghist[tid * nblk + b] = h[tid];
    ghist[(tid + 256) * nblk + b] = h[tid + 256];
}

// ---------- A2a: per-bucket exclusive scan of its nblk partials ----------
__global__ __launch_bounds__(256) void k_scanrow(int* __restrict__ ghist,
        int* __restrict__ tot, int nblk) {
    __shared__ int s[256];
    const int tid = threadIdx.x, b = blockIdx.x;
    int v = (tid < nblk) ? ghist[b * nblk + tid] : 0;
    s[tid] = v;
    __syncthreads();
    for (int off = 1; off < 256; off <<= 1) {
        int t = (tid >= off) ? s[tid - off] : 0;
        __syncthreads();
        s[tid] += t;
        __syncthreads();
    }
    if (tid < nblk) ghist[b * nblk + tid] = s[tid] - v;   // exclusive
    if (tid == 255) tot[b] = s[255];
}

// ---------- A2b: exclusive scan of 512 bucket totals -> base[513] ----------
__global__ __launch_bounds__(512) void k_base(const int* __restrict__ tot,
        int* __restrict__ base) {
    __shared__ int s[512];
    const int tid = threadIdx.x;
    int v = tot[tid];
    s[tid] = v;
    __syncthreads();
    for (int off = 1; off < 512; off <<= 1) {
        int t = (tid >= off) ? s[tid - off] : 0;
        __syncthreads();
        s[tid] += t;
        __syncthreads();
    }
    base[tid] = s[tid] - v;                   // exclusive
    if (tid == 511) base[512] = s[511];       // = E
}

// ---------- A3: partition scatter via LDS cursors (packed uint32) ----------
__global__ __launch_bounds__(256) void k_scatter_part(const int* __restrict__ src,
        const int* __restrict__ dst, const int* __restrict__ ghist,
        const int* __restrict__ base, unsigned* __restrict__ eb, int E, int nblk) {
    __shared__ int cur[NBUCKP];
    const int tid = threadIdx.x, b = blockIdx.x;
    cur[tid]       = ghist[tid * nblk + b] + base[tid];
    cur[tid + 256] = ghist[(tid + 256) * nblk + b] + base[tid + 256];
    __syncthreads();
    const int ebase = b * CHUNK;
#pragma unroll
    for (int i = 0; i < CHUNK / 256; ++i) {
        int e = ebase + i * 256 + tid;
        if (e < E) {
            int s = __builtin_nontemporal_load(&src[e]);
            int d = __builtin_nontemporal_load(&dst[e]);
            int pos = atomicAdd(&cur[d >> 8], 1);
            __builtin_nontemporal_store(((unsigned)(d & 255) << 24) | (unsigned)s,
                                        &eb[pos]);
        }
    }
}

// ---------- B: per-bucket CSR finalize (256 dst values per block) ----------
__global__ __launch_bounds__(256) void k_bucket_csr(const unsigned* __restrict__ eb,
        const int* __restrict__ base, int* __restrict__ row_ptr,
        float* __restrict__ dinv, int* __restrict__ col, int nblk, int N) {
    __shared__ int h[256], sc[256], cur[256];
    const int tid = threadIdx.x, k = blockIdx.x;
    const int bstart = base[k];
    const int bend   = base[k + 1];
    h[tid] = 0;
    __syncthreads();
    for (int e = bstart + tid; e < bend; e += 256)
        atomicAdd(&h[eb[e] >> 24], 1);
    __syncthreads();
    int v = h[tid];
    sc[tid] = v;
    __syncthreads();
    for (int off = 1; off < 256; off <<= 1) {
        int t = (tid >= off) ? sc[tid - off] : 0;
        __syncthreads();
        sc[tid] += t;
        __syncthreads();
    }
    int excl = sc[tid] - v;
    int n = k * 256 + tid;
    if (n < N) {
        row_ptr[n] = bstart + excl;
        dinv[n] = rsqrtf((float)v + 1.0f);    // +1 self-loop
        if (n == N - 1) row_ptr[N] = bstart + excl + v;
    }
    cur[tid] = excl;
    __syncthreads();
    for (int e = bstart + tid; e < bend; e += 256) {
        unsigned ed = eb[e];
        int pos = bstart + atomicAdd(&cur[ed >> 24], 1);
        __builtin_nontemporal_store((int)(ed & 0xFFFFFFu), &col[pos]);
    }
}

// ---------- MFMA GEMM: C[r][:] = bf16( dinv[r] * (A[r][:] @ B) ), K=128 ----------
template<int NC, bool ABF16>
__global__ __launch_bounds__(256) void k_gemm(const void* __restrict__ Av,
        const unsigned short* __restrict__ Wt, const float* __restrict__ dinv,
        unsigned short* __restrict__ C, int M) {
    __shared__ unsigned short sA[64][136];
    __shared__ unsigned short sW[NC][136];
    const int tid  = threadIdx.x;
    const int lane = tid & 63;
    const int wave = tid >> 6;
    const int row0 = blockIdx.x * 64;

    if (ABF16) {
        const uint4* A = (const uint4*)Av;
#pragma unroll
        for (int p = 0; p < 4; ++p) {
            int c = tid + p * 256;
            int row = c >> 4, cc = c & 15;
            uint4 v = make_uint4(0u, 0u, 0u, 0u);
            if (row0 + row < M) v = A[(size_t)(row0 + row) * 16 + cc];
            *(uint4*)&sA[row][cc * 8] = v;
        }
    } else {
        const float* A = (const float*)Av;
#pragma unroll
        for (int p = 0; p < 8; ++p) {
            int c = tid + p * 256;
            int row = c >> 5, c4 = (c & 31) * 4;
            float4 v = make_float4(0.f, 0.f, 0.f, 0.f);
            if (row0 + row < M) v = *(const float4*)&A[(size_t)(row0 + row) * 128 + c4];
            ushort4 o;
            o.x = f2bf(v.x); o.y = f2bf(v.y); o.z = f2bf(v.z); o.w = f2bf(v.w);
            *(ushort4*)&sA[row][c4] = o;
        }
    }
    {
        const uint4* W4 = (const uint4*)Wt;
#pragma unroll
        for (int p = 0; p < NC / 16; ++p) {
            int c = tid + p * 256;
            int n = c >> 4, cc = c & 15;
            *(uint4*)&sW[n][cc * 8] = W4[c];
        }
    }
    __syncthreads();

    constexpr int CT = NC / 64;
    const int colbase = wave * (NC / 4);
    const int frow = lane & 15;
    const int fk   = (lane >> 4) * 8;

    f32x4 acc[4][CT];
#pragma unroll
    for (int rt = 0; rt < 4; ++rt)
#pragma unroll
        for (int ct = 0; ct < CT; ++ct) acc[rt][ct] = (f32x4){0.f, 0.f, 0.f, 0.f};

#pragma unroll
    for (int kk = 0; kk < 128; kk += 32) {
        bf16x8 a[4], b[CT];
#pragma unroll
        for (int rt = 0; rt < 4; ++rt)
            a[rt] = *(const bf16x8*)&sA[rt * 16 + frow][kk + fk];
#pragma unroll
        for (int ct = 0; ct < CT; ++ct)
            b[ct] = *(const bf16x8*)&sW[colbase + ct * 16 + frow][kk + fk];
#pragma unroll
        for (int rt = 0; rt < 4; ++rt)
#pragma unroll
            for (int ct = 0; ct < CT; ++ct)
                acc[rt][ct] = __builtin_amdgcn_mfma_f32_16x16x32_bf16(
                    a[rt], b[ct], acc[rt][ct], 0, 0, 0);
    }

    const int crow = (lane >> 4) * 4;
#pragma unroll
    for (int rt = 0; rt < 4; ++rt) {
        int grow = row0 + rt * 16 + crow;
#pragma unroll
        for (int r = 0; r < 4; ++r) {
            if (grow + r < M) {
                float s = dinv[grow + r];
#pragma unroll
                for (int ct = 0; ct < CT; ++ct) {
                    int gcol = colbase + ct * 16 + (lane & 15);
                    C[(size_t)(grow + r) * NC + gcol] = f2bf(acc[rt][ct][r] * s);
                }
            }
        }
    }
}

// ---------- gather D=128: wave/node, half-wave slices, col-pipelined ----------
template<bool ELU>
__global__ __launch_bounds__(256) void k_gather128(const unsigned* __restrict__ H,
        const int* __restrict__ row_ptr, const int* __restrict__ col,
        const float* __restrict__ dinv, const float* __restrict__ bias,
        unsigned* __restrict__ outbf, int N) {
    const int wave = threadIdx.x >> 6, lane = threadIdx.x & 63;
    const int n = blockIdx.x * 4 + wave;
    if (n >= N) return;
    const int beg = row_ptr[n], end = row_ptr[n + 1];
    const int half = lane >> 5;
    const unsigned s2 = (unsigned)(lane & 31) * 2u;   // uint-index in row
    f32x4 acc = (f32x4){0.f, 0.f, 0.f, 0.f};

    if (half == 0) {                            // self row
        uint2 v = *(const uint2*)&H[((unsigned)n << 6) + s2];
        acc += bfquad(v);
    }
    int j = beg + half;
    // 4-deep main loop with next-iteration col prefetch; col is stream-once
    int c0, c1, c2, c3;
    bool have = (j + 6 < end);
    if (have) {
        c0 = __builtin_nontemporal_load(&col[j]);
        c1 = __builtin_nontemporal_load(&col[j + 2]);
        c2 = __builtin_nontemporal_load(&col[j + 4]);
        c3 = __builtin_nontemporal_load(&col[j + 6]);
    }
    while (have) {
        int jn = j + 8;
        bool haven = (jn + 6 < end);
        int d0 = c0, d1 = c0, d2 = c0, d3 = c0;
        if (haven) {
            d0 = __builtin_nontemporal_load(&col[jn]);
            d1 = __builtin_nontemporal_load(&col[jn + 2]);
            d2 = __builtin_nontemporal_load(&col[jn + 4]);
            d3 = __builtin_nontemporal_load(&col[jn + 6]);
        }
        uint2 v0 = *(const uint2*)&H[((unsigned)c0 << 6) + s2];
        uint2 v1 = *(const uint2*)&H[((unsigned)c1 << 6) + s2];
        uint2 v2 = *(const uint2*)&H[((unsigned)c2 << 6) + s2];
        uint2 v3 = *(const uint2*)&H[((unsigned)c3 << 6) + s2];
        acc += bfquad(v0);
        acc += bfquad(v1);
        acc += bfquad(v2);
        acc += bfquad(v3);
        j = jn; c0 = d0; c1 = d1; c2 = d2; c3 = d3; have = haven;
    }
    if (j < end) {                              // predicated tail (<=3 items)
        const int e1 = end - 1;
        int j1 = j + 2, j2 = j + 4;
        int t0 = col[j];
        int t1 = col[j1 <= e1 ? j1 : e1];       // clamped: cache-hot row
        int t2 = col[j2 <= e1 ? j2 : e1];
        float w1 = (j1 < end) ? 1.f : 0.f;
        float w2 = (j2 < end) ? 1.f : 0.f;
        uint2 v0 = *(const uint2*)&H[((unsigned)t0 << 6) + s2];
        uint2 v1 = *(const uint2*)&H[((unsigned)t1 << 6) + s2];
        uint2 v2 = *(const uint2*)&H[((unsigned)t2 << 6) + s2];
        acc += bfquad(v0);
        acc += bfquad(v1) * w1;
        acc += bfquad(v2) * w2;
    }

    float a0 = acc[0], a1 = acc[1], a2 = acc[2], a3 = acc[3];
    a0 += __shfl_xor(a0, 32); a1 += __shfl_xor(a1, 32);
    a2 += __shfl_xor(a2, 32); a3 += __shfl_xor(a3, 32);
    if (half == 0) {
        float sc = dinv[n];
        float4 b = *(const float4*)&bias[2 * s2];
        float o0 = fmaf(a0, sc, b.x), o1 = fmaf(a1, sc, b.y);
        float o2 = fmaf(a2, sc, b.z), o3 = fmaf(a3, sc, b.w);
        if (ELU) {
            o0 = o0 > 0.f ? o0 : expm1f(o0);
            o1 = o1 > 0.f ? o1 : expm1f(o1);
            o2 = o2 > 0.f ? o2 : expm1f(o2);
            o3 = o3 > 0.f ? o3 : expm1f(o3);
        }
        u32x2 o;
        o[0] = (unsigned)f2bf(o0) | ((unsigned)f2bf(o1) << 16);
        o[1] = (unsigned)f2bf(o2) | ((unsigned)f2bf(o3) << 16);
        __builtin_nontemporal_store(o, (u32x2*)&outbf[((unsigned)n << 6) + s2]);
    }
}

// ---------- gather D=64: quarter-wave slices, 4-deep, col-pipelined ----------
__global__ __launch_bounds__(256) void k_gather64(const unsigned* __restrict__ H,
        const int* __restrict__ row_ptr, const int* __restrict__ col,
        const float* __restrict__ dinv, const float* __restrict__ bias,
        float* __restrict__ out, int N) {
    const int wave = threadIdx.x >> 6, lane = threadIdx.x & 63;
    const int n = blockIdx.x * 4 + wave;
    if (n >= N) return;
    const int beg = row_ptr[n], end = row_ptr[n + 1];
    const int q = lane >> 4;
    const unsigned s2 = (unsigned)(lane & 15) * 2u;
    f32x4 acc = (f32x4){0.f, 0.f, 0.f, 0.f};

    if (q == 0) {                               // self row
        uint2 v = *(const uint2*)&H[((unsigned)n << 5) + s2];
        acc += bfquad(v);
    }
    int j = beg + q;
    int c0, c1, c2, c3;
    bool have = (j + 12 < end);
    if (have) {
        c0 = __builtin_nontemporal_load(&col[j]);
        c1 = __builtin_nontemporal_load(&col[j + 4]);
        c2 = __builtin_nontemporal_load(&col[j + 8]);
        c3 = __builtin_nontemporal_load(&col[j + 12]);
    }
    while (have) {
        int jn = j + 16;
        bool haven = (jn + 12 < end);
        int d0 = c0, d1 = c0, d2 = c0, d3 = c0;
        if (haven) {
            d0 = __builtin_nontemporal_load(&col[jn]);
            d1 = __builtin_nontemporal_load(&col[jn + 4]);
            d2 = __builtin_nontemporal_load(&col[jn + 8]);
            d3 = __builtin_nontemporal_load(&col[jn + 12]);
        }
        uint2 v0 = *(const uint2*)&H[((unsigned)c0 << 5) + s2];
        uint2 v1 = *(const uint2*)&H[((unsigned)c1 << 5) + s2];
        uint2 v2 = *(const uint2*)&H[((unsigned)c2 << 5) + s2];
        uint2 v3 = *(const uint2*)&H[((unsigned)c3 << 5) + s2];
        acc += bfquad(v0);
        acc += bfquad(v1);
        acc += bfquad(v2);
        acc += bfquad(v3);
        j = jn; c0 = d0; c1 = d1; c2 = d2; c3 = d3; have = haven;
    }
    if (j < end) {                              // predicated tail (<=3 items)
        const int e1 = end - 1;
        int j1 = j + 4, j2 = j + 8;
        int t0 = col[j];
        int t1 = col[j1 <= e1 ? j1 : e1];
        int t2 = col[j2 <= e1 ? j2 : e1];
        float w1 = (j1 < end) ? 1.f : 0.f;
        float w2 = (j2 < end) ? 1.f : 0.f;
        uint2 v0 = *(const uint2*)&H[((unsigned)t0 << 5) + s2];
        uint2 v1 = *(const uint2*)&H[((unsigned)t1 << 5) + s2];
        uint2 v2 = *(const uint2*)&H[((unsigned)t2 << 5) + s2];
        acc += bfquad(v0);
        acc += bfquad(v1) * w1;
        acc += bfquad(v2) * w2;
    }

    float a0 = acc[0], a1 = acc[1], a2 = acc[2], a3 = acc[3];
    a0 += __shfl_xor(a0, 16); a1 += __shfl_xor(a1, 16);
    a2 += __shfl_xor(a2, 16); a3 += __shfl_xor(a3, 16);
    a0 += __shfl_xor(a0, 32); a1 += __shfl_xor(a1, 32);
    a2 += __shfl_xor(a2, 32); a3 += __shfl_xor(a3, 32);
    if (q == 0) {
        float sc = dinv[n];
        float4 b = *(const float4*)&bias[2 * s2];
        f32x4 o;
        o[0] = fmaf(a0, sc, b.x); o[1] = fmaf(a1, sc, b.y);
        o[2] = fmaf(a2, sc, b.z); o[3] = fmaf(a3, sc, b.w);
        __builtin_nontemporal_store(o, (f32x4*)&out[((unsigned)n << 6) + 2 * s2]);
    }
}

extern "C" void kernel_launch(void* const* d_in, const int* in_sizes, int n_in,
                              void* d_out, int out_size, void* d_ws, size_t ws_size,
                              hipStream_t stream) {
    const float* x  = (const float*)d_in[0];
    const int*   ei = (const int*)d_in[1];
    const float* W1 = (const float*)d_in[2];
    const float* b1 = (const float*)d_in[3];
    const float* W2 = (const float*)d_in[4];
    const float* b2 = (const float*)d_in[5];
    float* out = (float*)d_out;

    const int N = in_sizes[0] / 128;   // 100000
    const int E = in_sizes[1] / 2;     // 800000
    const int* src = ei;
    const int* dst = ei + E;
    const int NPAD = (N + 63) & ~63;

    const int NBLK_A = (E + CHUNK - 1) / CHUNK;        // 196
    const int L      = NBUCKP * NBLK_A;                // 100352
    const int NBUCK  = (N + 255) / 256;                // 391

    // workspace layout (4-byte units)
    unsigned off = 0;
    int* row_ptr    = (int*)d_ws + off;            off += NPAD + 64;
    float* dinv     = (float*)((int*)d_ws + off);  off += NPAD + 64;
    int* ghist      = (int*)d_ws + off;            off += (unsigned)((L + 63) & ~63);
    int* tot        = (int*)d_ws + off;            off += 512;
    int* base       = (int*)d_ws + off;            off += 576;
    unsigned* eb    = (unsigned*)((int*)d_ws + off); off += (unsigned)((E + 63) & ~63);
    int* col        = (int*)d_ws + off;            off += (unsigned)((E + 63) & ~63);
    unsigned short* W1t = (unsigned short*)((int*)d_ws + off); off += 8192;
    unsigned short* W2t = (unsigned short*)((int*)d_ws + off); off += 4096;
    unsigned* H     = (unsigned*)((int*)d_ws + off); off += (unsigned)N * 64 + 64;
    unsigned* act   = (unsigned*)((int*)d_ws + off);

    // CSR build (no global atomics) + fused W prep
    k_hist<<<NBLK_A + 96, 256, 0, stream>>>(dst, ghist, E, NBLK_A, W1, W2, W1t, W2t);
    k_scanrow<<<NBUCKP, 256, 0, stream>>>(ghist, tot, NBLK_A);
    k_base<<<1, 512, 0, stream>>>(tot, base);
    k_scatter_part<<<NBLK_A, 256, 0, stream>>>(src, dst, ghist, base, eb, E, NBLK_A);
    k_bucket_csr<<<NBUCK, 256, 0, stream>>>(eb, base, row_ptr, dinv, col, NBLK_A, N);

    // Layer 1
    k_gemm<128, false><<<(N + 63) / 64, 256, 0, stream>>>(x, W1t, dinv,
                                                          (unsigned short*)H, N);
    k_gather128<true><<<(N + 3) / 4, 256, 0, stream>>>(H, row_ptr, col, dinv, b1, act, N);

    // Layer 2
    k_gemm<64, true><<<(N + 63) / 64, 256, 0, stream>>>(act, W2t, dinv,
                                                        (unsigned short*)H, N);
    k_gather64<<<(N + 3) / 4, 256, 0, stream>>>(H, row_ptr, col, dinv, b2, out, N);
}

// Round 11
// 151.155 us; speedup vs baseline: 1.2091x; 1.2091x over previous
//
#include <hip/hip_runtime.h>

// WalletGNN: 2-layer GCN, N=100000, E=800000, 128 -> 128 -> 64, fp32 in/out.
// R11: revert ALL nontemporal hints from R10 (nt col loads broke line reuse;
//      nt stores to act/eb/col forced consumers to L3/HBM — net -30us).
//      Keep R10's consolidated 2-kernel scan chain. Gathers = R9 structure.

typedef __attribute__((ext_vector_type(8))) short bf16x8;
typedef __attribute__((ext_vector_type(4))) float f32x4;

static __device__ __forceinline__ unsigned short f2bf(float f) {
    unsigned u = __builtin_bit_cast(unsigned, f);
    u += 0x7fffu + ((u >> 16) & 1u);
    return (unsigned short)(u >> 16);
}
static __device__ __forceinline__ float bflo(unsigned u) {
    return __builtin_bit_cast(float, u << 16);
}
// {lo(x), hi(x)+junk, lo(y), hi(y)+junk} — junk mantissa < 2^-8 relative.
static __device__ __forceinline__ f32x4 bfquad(uint2 v) {
    f32x4 r;
    r[0] = bflo(v.x); r[1] = __builtin_bit_cast(float, v.x);
    r[2] = bflo(v.y); r[3] = __builtin_bit_cast(float, v.y);
    return r;
}

#define CHUNK 4096              // edges per partition block
#define NBUCKP 512              // padded bucket count (dst>>8 < 391)

// ---------- A1: per-block bucket histogram (+fused W^T bf16 prep) ----------
__global__ __launch_bounds__(256) void k_hist(const int* __restrict__ dst,
        int* __restrict__ ghist, int E, int nblk,
        const float* __restrict__ W1, const float* __restrict__ W2,
        unsigned short* __restrict__ W1t, unsigned short* __restrict__ W2t) {
    __shared__ int h[NBUCKP];
    const int tid = threadIdx.x, b = blockIdx.x;
    if (b >= nblk) {            // prep_w blocks
        int i = (b - nblk) * 256 + tid;
        if (i < 128 * 128) {
            int n = i >> 7, k = i & 127;
            W1t[i] = f2bf(W1[k * 128 + n]);
        }
        int j = i - 128 * 128;
        if (j >= 0 && j < 64 * 128) {
            int n = j >> 7, k = j & 127;
            W2t[j] = f2bf(W2[k * 64 + n]);
        }
        return;
    }
    h[tid] = 0; h[tid + 256] = 0;
    __syncthreads();
    const int base = b * CHUNK;
#pragma unroll
    for (int i = 0; i < CHUNK / 256; ++i) {
        int e = base + i * 256 + tid;
        if (e < E) atomicAdd(&h[dst[e] >> 8], 1);
    }
    __syncthreads();
    ghist[tid * nblk + b] = h[tid];
    ghist[(tid + 256) * nblk + b] = h[tid + 256];
}

// ---------- A2a: per-bucket exclusive scan of its nblk partials ----------
__global__ __launch_bounds__(256) void k_scanrow(int* __restrict__ ghist,
        int* __restrict__ tot, int nblk) {
    __shared__ int s[256];
    const int tid = threadIdx.x, b = blockIdx.x;
    int v = (tid < nblk) ? ghist[b * nblk + tid] : 0;
    s[tid] = v;
    __syncthreads();
    for (int off = 1; off < 256; off <<= 1) {
        int t = (tid >= off) ? s[tid - off] : 0;
        __syncthreads();
        s[tid] += t;
        __syncthreads();
    }
    if (tid < nblk) ghist[b * nblk + tid] = s[tid] - v;   // exclusive
    if (tid == 255) tot[b] = s[255];
}

// ---------- A2b: exclusive scan of 512 bucket totals -> base[513] ----------
__global__ __launch_bounds__(512) void k_base(const int* __restrict__ tot,
        int* __restrict__ base) {
    __shared__ int s[512];
    const int tid = threadIdx.x;
    int v = tot[tid];
    s[tid] = v;
    __syncthreads();
    for (int off = 1; off < 512; off <<= 1) {
        int t = (tid >= off) ? s[tid - off] : 0;
        __syncthreads();
        s[tid] += t;
        __syncthreads();
    }
    base[tid] = s[tid] - v;                   // exclusive
    if (tid == 511) base[512] = s[511];       // = E
}

// ---------- A3: partition scatter via LDS cursors (packed uint32) ----------
__global__ __launch_bounds__(256) void k_scatter_part(const int* __restrict__ src,
        const int* __restrict__ dst, const int* __restrict__ ghist,
        const int* __restrict__ base, unsigned* __restrict__ eb, int E, int nblk) {
    __shared__ int cur[NBUCKP];
    const int tid = threadIdx.x, b = blockIdx.x;
    cur[tid]       = ghist[tid * nblk + b] + base[tid];
    cur[tid + 256] = ghist[(tid + 256) * nblk + b] + base[tid + 256];
    __syncthreads();
    const int ebase = b * CHUNK;
#pragma unroll
    for (int i = 0; i < CHUNK / 256; ++i) {
        int e = ebase + i * 256 + tid;
        if (e < E) {
            int s = src[e], d = dst[e];
            int pos = atomicAdd(&cur[d >> 8], 1);
            eb[pos] = ((unsigned)(d & 255) << 24) | (unsigned)s;
        }
    }
}

// ---------- B: per-bucket CSR finalize (256 dst values per block) ----------
__global__ __launch_bounds__(256) void k_bucket_csr(const unsigned* __restrict__ eb,
        const int* __restrict__ base, int* __restrict__ row_ptr,
        float* __restrict__ dinv, int* __restrict__ col, int nblk, int N) {
    __shared__ int h[256], sc[256], cur[256];
    const int tid = threadIdx.x, k = blockIdx.x;
    const int bstart = base[k];
    const int bend   = base[k + 1];
    h[tid] = 0;
    __syncthreads();
    for (int e = bstart + tid; e < bend; e += 256)
        atomicAdd(&h[eb[e] >> 24], 1);
    __syncthreads();
    int v = h[tid];
    sc[tid] = v;
    __syncthreads();
    for (int off = 1; off < 256; off <<= 1) {
        int t = (tid >= off) ? sc[tid - off] : 0;
        __syncthreads();
        sc[tid] += t;
        __syncthreads();
    }
    int excl = sc[tid] - v;
    int n = k * 256 + tid;
    if (n < N) {
        row_ptr[n] = bstart + excl;
        dinv[n] = rsqrtf((float)v + 1.0f);    // +1 self-loop
        if (n == N - 1) row_ptr[N] = bstart + excl + v;
    }
    cur[tid] = excl;
    __syncthreads();
    for (int e = bstart + tid; e < bend; e += 256) {
        unsigned ed = eb[e];
        int pos = bstart + atomicAdd(&cur[ed >> 24], 1);
        col[pos] = (int)(ed & 0xFFFFFFu);
    }
}

// ---------- MFMA GEMM: C[r][:] = bf16( dinv[r] * (A[r][:] @ B) ), K=128 ----------
template<int NC, bool ABF16>
__global__ __launch_bounds__(256) void k_gemm(const void* __restrict__ Av,
        const unsigned short* __restrict__ Wt, const float* __restrict__ dinv,
        unsigned short* __restrict__ C, int M) {
    __shared__ unsigned short sA[64][136];
    __shared__ unsigned short sW[NC][136];
    const int tid  = threadIdx.x;
    const int lane = tid & 63;
    const int wave = tid >> 6;
    const int row0 = blockIdx.x * 64;

    if (ABF16) {
        const uint4* A = (const uint4*)Av;
#pragma unroll
        for (int p = 0; p < 4; ++p) {
            int c = tid + p * 256;
            int row = c >> 4, cc = c & 15;
            uint4 v = make_uint4(0u, 0u, 0u, 0u);
            if (row0 + row < M) v = A[(size_t)(row0 + row) * 16 + cc];
            *(uint4*)&sA[row][cc * 8] = v;
        }
    } else {
        const float* A = (const float*)Av;
#pragma unroll
        for (int p = 0; p < 8; ++p) {
            int c = tid + p * 256;
            int row = c >> 5, c4 = (c & 31) * 4;
            float4 v = make_float4(0.f, 0.f, 0.f, 0.f);
            if (row0 + row < M) v = *(const float4*)&A[(size_t)(row0 + row) * 128 + c4];
            ushort4 o;
            o.x = f2bf(v.x); o.y = f2bf(v.y); o.z = f2bf(v.z); o.w = f2bf(v.w);
            *(ushort4*)&sA[row][c4] = o;
        }
    }
    {
        const uint4* W4 = (const uint4*)Wt;
#pragma unroll
        for (int p = 0; p < NC / 16; ++p) {
            int c = tid + p * 256;
            int n = c >> 4, cc = c & 15;
            *(uint4*)&sW[n][cc * 8] = W4[c];
        }
    }
    __syncthreads();

    constexpr int CT = NC / 64;
    const int colbase = wave * (NC / 4);
    const int frow = lane & 15;
    const int fk   = (lane >> 4) * 8;

    f32x4 acc[4][CT];
#pragma unroll
    for (int rt = 0; rt < 4; ++rt)
#pragma unroll
        for (int ct = 0; ct < CT; ++ct) acc[rt][ct] = (f32x4){0.f, 0.f, 0.f, 0.f};

#pragma unroll
    for (int kk = 0; kk < 128; kk += 32) {
        bf16x8 a[4], b[CT];
#pragma unroll
        for (int rt = 0; rt < 4; ++rt)
            a[rt] = *(const bf16x8*)&sA[rt * 16 + frow][kk + fk];
#pragma unroll
        for (int ct = 0; ct < CT; ++ct)
            b[ct] = *(const bf16x8*)&sW[colbase + ct * 16 + frow][kk + fk];
#pragma unroll
        for (int rt = 0; rt < 4; ++rt)
#pragma unroll
            for (int ct = 0; ct < CT; ++ct)
                acc[rt][ct] = __builtin_amdgcn_mfma_f32_16x16x32_bf16(
                    a[rt], b[ct], acc[rt][ct], 0, 0, 0);
    }

    const int crow = (lane >> 4) * 4;
#pragma unroll
    for (int rt = 0; rt < 4; ++rt) {
        int grow = row0 + rt * 16 + crow;
#pragma unroll
        for (int r = 0; r < 4; ++r) {
            if (grow + r < M) {
                float s = dinv[grow + r];
#pragma unroll
                for (int ct = 0; ct < CT; ++ct) {
                    int gcol = colbase + ct * 16 + (lane & 15);
                    C[(size_t)(grow + r) * NC + gcol] = f2bf(acc[rt][ct][r] * s);
                }
            }
        }
    }
}

// ---------- gather D=128: wave/node, half-wave slices, col-pipelined ----------
template<bool ELU>
__global__ __launch_bounds__(256) void k_gather128(const unsigned* __restrict__ H,
        const int* __restrict__ row_ptr, const int* __restrict__ col,
        const float* __restrict__ dinv, const float* __restrict__ bias,
        unsigned* __restrict__ outbf, int N) {
    const int wave = threadIdx.x >> 6, lane = threadIdx.x & 63;
    const int n = blockIdx.x * 4 + wave;
    if (n >= N) return;
    const int beg = row_ptr[n], end = row_ptr[n + 1];
    const int half = lane >> 5;
    const unsigned s2 = (unsigned)(lane & 31) * 2u;   // uint-index in row
    f32x4 acc = (f32x4){0.f, 0.f, 0.f, 0.f};

    if (half == 0) {                            // self row
        uint2 v = *(const uint2*)&H[((unsigned)n << 6) + s2];
        acc += bfquad(v);
    }
    int j = beg + half;
    // 4-deep main loop with next-iteration col prefetch
    int c0, c1, c2, c3;
    bool have = (j + 6 < end);
    if (have) { c0 = col[j]; c1 = col[j + 2]; c2 = col[j + 4]; c3 = col[j + 6]; }
    while (have) {
        int jn = j + 8;
        bool haven = (jn + 6 < end);
        int d0 = c0, d1 = c0, d2 = c0, d3 = c0;
        if (haven) { d0 = col[jn]; d1 = col[jn + 2]; d2 = col[jn + 4]; d3 = col[jn + 6]; }
        uint2 v0 = *(const uint2*)&H[((unsigned)c0 << 6) + s2];
        uint2 v1 = *(const uint2*)&H[((unsigned)c1 << 6) + s2];
        uint2 v2 = *(const uint2*)&H[((unsigned)c2 << 6) + s2];
        uint2 v3 = *(const uint2*)&H[((unsigned)c3 << 6) + s2];
        acc += bfquad(v0);
        acc += bfquad(v1);
        acc += bfquad(v2);
        acc += bfquad(v3);
        j = jn; c0 = d0; c1 = d1; c2 = d2; c3 = d3; have = haven;
    }
    if (j < end) {                              // predicated tail (<=3 items)
        const int e1 = end - 1;
        int j1 = j + 2, j2 = j + 4;
        int t0 = col[j];
        int t1 = col[j1 <= e1 ? j1 : e1];       // clamped: cache-hot row
        int t2 = col[j2 <= e1 ? j2 : e1];
        float w1 = (j1 < end) ? 1.f : 0.f;
        float w2 = (j2 < end) ? 1.f : 0.f;
        uint2 v0 = *(const uint2*)&H[((unsigned)t0 << 6) + s2];
        uint2 v1 = *(const uint2*)&H[((unsigned)t1 << 6) + s2];
        uint2 v2 = *(const uint2*)&H[((unsigned)t2 << 6) + s2];
        acc += bfquad(v0);
        acc += bfquad(v1) * w1;
        acc += bfquad(v2) * w2;
    }

    float a0 = acc[0], a1 = acc[1], a2 = acc[2], a3 = acc[3];
    a0 += __shfl_xor(a0, 32); a1 += __shfl_xor(a1, 32);
    a2 += __shfl_xor(a2, 32); a3 += __shfl_xor(a3, 32);
    if (half == 0) {
        float sc = dinv[n];
        float4 b = *(const float4*)&bias[2 * s2];
        float o0 = fmaf(a0, sc, b.x), o1 = fmaf(a1, sc, b.y);
        float o2 = fmaf(a2, sc, b.z), o3 = fmaf(a3, sc, b.w);
        if (ELU) {
            o0 = o0 > 0.f ? o0 : expm1f(o0);
            o1 = o1 > 0.f ? o1 : expm1f(o1);
            o2 = o2 > 0.f ? o2 : expm1f(o2);
            o3 = o3 > 0.f ? o3 : expm1f(o3);
        }
        uint2 o;
        o.x = (unsigned)f2bf(o0) | ((unsigned)f2bf(o1) << 16);
        o.y = (unsigned)f2bf(o2) | ((unsigned)f2bf(o3) << 16);
        *(uint2*)&outbf[((unsigned)n << 6) + s2] = o;
    }
}

// ---------- gather D=64: quarter-wave slices, 4-deep, col-pipelined ----------
__global__ __launch_bounds__(256) void k_gather64(const unsigned* __restrict__ H,
        const int* __restrict__ row_ptr, const int* __restrict__ col,
        const float* __restrict__ dinv, const float* __restrict__ bias,
        float* __restrict__ out, int N) {
    const int wave = threadIdx.x >> 6, lane = threadIdx.x & 63;
    const int n = blockIdx.x * 4 + wave;
    if (n >= N) return;
    const int beg = row_ptr[n], end = row_ptr[n + 1];
    const int q = lane >> 4;
    const unsigned s2 = (unsigned)(lane & 15) * 2u;
    f32x4 acc = (f32x4){0.f, 0.f, 0.f, 0.f};

    if (q == 0) {                               // self row
        uint2 v = *(const uint2*)&H[((unsigned)n << 5) + s2];
        acc += bfquad(v);
    }
    int j = beg + q;
    int c0, c1, c2, c3;
    bool have = (j + 12 < end);
    if (have) { c0 = col[j]; c1 = col[j + 4]; c2 = col[j + 8]; c3 = col[j + 12]; }
    while (have) {
        int jn = j + 16;
        bool haven = (jn + 12 < end);
        int d0 = c0, d1 = c0, d2 = c0, d3 = c0;
        if (haven) { d0 = col[jn]; d1 = col[jn + 4]; d2 = col[jn + 8]; d3 = col[jn + 12]; }
        uint2 v0 = *(const uint2*)&H[((unsigned)c0 << 5) + s2];
        uint2 v1 = *(const uint2*)&H[((unsigned)c1 << 5) + s2];
        uint2 v2 = *(const uint2*)&H[((unsigned)c2 << 5) + s2];
        uint2 v3 = *(const uint2*)&H[((unsigned)c3 << 5) + s2];
        acc += bfquad(v0);
        acc += bfquad(v1);
        acc += bfquad(v2);
        acc += bfquad(v3);
        j = jn; c0 = d0; c1 = d1; c2 = d2; c3 = d3; have = haven;
    }
    if (j < end) {                              // predicated tail (<=3 items)
        const int e1 = end - 1;
        int j1 = j + 4, j2 = j + 8;
        int t0 = col[j];
        int t1 = col[j1 <= e1 ? j1 : e1];
        int t2 = col[j2 <= e1 ? j2 : e1];
        float w1 = (j1 < end) ? 1.f : 0.f;
        float w2 = (j2 < end) ? 1.f : 0.f;
        uint2 v0 = *(const uint2*)&H[((unsigned)t0 << 5) + s2];
        uint2 v1 = *(const uint2*)&H[((unsigned)t1 << 5) + s2];
        uint2 v2 = *(const uint2*)&H[((unsigned)t2 << 5) + s2];
        acc += bfquad(v0);
        acc += bfquad(v1) * w1;
        acc += bfquad(v2) * w2;
    }

    float a0 = acc[0], a1 = acc[1], a2 = acc[2], a3 = acc[3];
    a0 += __shfl_xor(a0, 16); a1 += __shfl_xor(a1, 16);
    a2 += __shfl_xor(a2, 16); a3 += __shfl_xor(a3, 16);
    a0 += __shfl_xor(a0, 32); a1 += __shfl_xor(a1, 32);
    a2 += __shfl_xor(a2, 32); a3 += __shfl_xor(a3, 32);
    if (q == 0) {
        float sc = dinv[n];
        float4 b = *(const float4*)&bias[2 * s2];
        float4 o;
        o.x = fmaf(a0, sc, b.x); o.y = fmaf(a1, sc, b.y);
        o.z = fmaf(a2, sc, b.z); o.w = fmaf(a3, sc, b.w);
        *(float4*)&out[((unsigned)n << 6) + 2 * s2] = o;
    }
}

extern "C" void kernel_launch(void* const* d_in, const int* in_sizes, int n_in,
                              void* d_out, int out_size, void* d_ws, size_t ws_size,
                              hipStream_t stream) {
    const float* x  = (const float*)d_in[0];
    const int*   ei = (const int*)d_in[1];
    const float* W1 = (const float*)d_in[2];
    const float* b1 = (const float*)d_in[3];
    const float* W2 = (const float*)d_in[4];
    const float* b2 = (const float*)d_in[5];
    float* out = (float*)d_out;

    const int N = in_sizes[0] / 128;   // 100000
    const int E = in_sizes[1] / 2;     // 800000
    const int* src = ei;
    const int* dst = ei + E;
    const int NPAD = (N + 63) & ~63;

    const int NBLK_A = (E + CHUNK - 1) / CHUNK;        // 196
    const int L      = NBUCKP * NBLK_A;                // 100352
    const int NBUCK  = (N + 255) / 256;                // 391

    // workspace layout (4-byte units)
    unsigned off = 0;
    int* row_ptr    = (int*)d_ws + off;            off += NPAD + 64;
    float* dinv     = (float*)((int*)d_ws + off);  off += NPAD + 64;
    int* ghist      = (int*)d_ws + off;            off += (unsigned)((L + 63) & ~63);
    int* tot        = (int*)d_ws + off;            off += 512;
    int* base       = (int*)d_ws + off;            off += 576;
    unsigned* eb    = (unsigned*)((int*)d_ws + off); off += (unsigned)((E + 63) & ~63);
    int* col        = (int*)d_ws + off;            off += (unsigned)((E + 63) & ~63);
    unsigned short* W1t = (unsigned short*)((int*)d_ws + off); off += 8192;
    unsigned short* W2t = (unsigned short*)((int*)d_ws + off); off += 4096;
    unsigned* H     = (unsigned*)((int*)d_ws + off); off += (unsigned)N * 64 + 64;
    unsigned* act   = (unsigned*)((int*)d_ws + off);

    // CSR build (no global atomics) + fused W prep
    k_hist<<<NBLK_A + 96, 256, 0, stream>>>(dst, ghist, E, NBLK_A, W1, W2, W1t, W2t);
    k_scanrow<<<NBUCKP, 256, 0, stream>>>(ghist, tot, NBLK_A);
    k_base<<<1, 512, 0, stream>>>(tot, base);
    k_scatter_part<<<NBLK_A, 256, 0, stream>>>(src, dst, ghist, base, eb, E, NBLK_A);
    k_bucket_csr<<<NBUCK, 256, 0, stream>>>(eb, base, row_ptr, dinv, col, NBLK_A, N);

    // Layer 1
    k_gemm<128, false><<<(N + 63) / 64, 256, 0, stream>>>(x, W1t, dinv,
                                                          (unsigned short*)H, N);
    k_gather128<true><<<(N + 3) / 4, 256, 0, stream>>>(H, row_ptr, col, dinv, b1, act, N);

    // Layer 2
    k_gemm<64, true><<<(N + 63) / 64, 256, 0, stream>>>(act, W2t, dinv,
                                                        (unsigned short*)H, N);
    k_gather64<<<(N + 3) / 4, 256, 0, stream>>>(H, row_ptr, col, dinv, b2, out, N);
}